// Round 3
// baseline (233.252 us; speedup 1.0000x reference)
//
#include <hip/hip_runtime.h>
#include <hip/hip_bf16.h>
#include <float.h>

// B=4096, D=512, N=8192, temp=0.5
#define BN_ 4096
#define DD  512
#define NN  8192
#define SCALE 2.0f   // 1/temperature
#define BUF 16384    // elements per LDS K-tile buffer (256 rows x 64 K)
#define NTILE 528    // 32*33/2 lower-triangle 256x256 tiles
#define GRIDG 512    // gram grid; blocks 0-15 take a second tile
#define NDUTY 32     // last finishers that run the fused lse

typedef unsigned short u16;
typedef __attribute__((ext_vector_type(8))) short short8;   // 8 bf16 = 4 VGPRs
typedef __attribute__((ext_vector_type(4))) float floatx4;  // MFMA acc

struct alignas(8) U16x4 { u16 x, y, z, w; };

__device__ __forceinline__ u16 f2bf(float f) {
    union { float f; unsigned u; } c; c.f = f;
    unsigned u = c.u;
    unsigned r = (u + 0x7fffu + ((u >> 16) & 1u)) >> 16;   // RNE
    return (u16)r;
}

__device__ __forceinline__ void async_copy16(const u16* g, u16* l) {
    __builtin_amdgcn_global_load_lds(
        (const __attribute__((address_space(1))) void*)g,
        (__attribute__((address_space(3))) void*)l, 16, 0, 0);
}

// ------ kernel 1: fp32 -> bf16 concat + per-block positive-dot partial ------
// block 0 zero-inits d_out and the gram ticket (harness poisons d_out).
__global__ __launch_bounds__(256) void convert_pos_kernel(const float* __restrict__ hi,
                                                          const float* __restrict__ hj,
                                                          u16* __restrict__ H,
                                                          float* __restrict__ Pos,
                                                          float* __restrict__ out,
                                                          unsigned* __restrict__ ticket) {
    __shared__ float red[4];
    int t = blockIdx.x * 256 + threadIdx.x;     // 2048 blocks -> 524288 threads
    int e = t * 4;
    const int BD = BN_ * DD;
    float4 a = *(const float4*)(hi + e);
    float4 b = *(const float4*)(hj + e);
    U16x4 oa, ob;
    oa.x = f2bf(a.x); oa.y = f2bf(a.y); oa.z = f2bf(a.z); oa.w = f2bf(a.w);
    ob.x = f2bf(b.x); ob.y = f2bf(b.y); ob.z = f2bf(b.z); ob.w = f2bf(b.w);
    *(U16x4*)(H + e) = oa;
    *(U16x4*)(H + BD + e) = ob;
    float dot = a.x * b.x + a.y * b.y + a.z * b.z + a.w * b.w;
#pragma unroll
    for (int msk = 1; msk < 64; msk <<= 1) dot += __shfl_xor(dot, msk);
    int lane = threadIdx.x & 63, wid = threadIdx.x >> 6;
    if (lane == 0) red[wid] = dot;
    __syncthreads();
    if (threadIdx.x == 0) {
        Pos[blockIdx.x] = red[0] + red[1] + red[2] + red[3];
        if (blockIdx.x == 0) { *out = 0.0f; *ticket = 0u; }
    }
}

// ------------- kernel 2: symmetric Gram + fused final LSE -------------
// 256^2 tiles, 8 waves (2Mx4N), BK=64, double-buffered 128 KiB LDS.
// Per K-tile: { vmcnt(8); barrier; COMPUTE whole tile; barrier; stage(t+2) }.
// Counted vmcnt never drains in-loop (stage has a full tile of slack); the
// stage is issued AFTER the barrier that proves all waves finished reading
// that buffer.  LDS layout [row:256][chunk:8] 16B chunks, ck^(row&7) swizzle
// applied on the SOURCE address (linear global_load_lds dest), matched on
// ds_read -> conflict-free (verified: SQ_LDS_BANK_CONFLICT = 0 in r2).
// Grid 512 (bijective XCD swizzle); blocks 0-15 run a second tile.  After a
// block's partials are published it draws a ticket; the last 32 finishers
// reduce 256 rows each (fused lse) -- saves the third kernel launch.
#define MFMA_(va, vb, c) __builtin_amdgcn_mfma_f32_16x16x32_bf16(va, vb, c, 0, 0, 0)

#define MF_ROW(mi, areg)                       \
    acc[mi][0] = MFMA_(areg, b0, acc[mi][0]);  \
    acc[mi][1] = MFMA_(areg, b1, acc[mi][1]);  \
    acc[mi][2] = MFMA_(areg, b2, acc[mi][2]);  \
    acc[mi][3] = MFMA_(areg, b3, acc[mi][3]);

#define VMWAIT(n) asm volatile("s_waitcnt vmcnt(" #n ")" ::: "memory")

#define STAGE_T(kb, pA, pB) {                          \
    async_copy16(HA + so0 + (kb), (pA) + dd0);         \
    async_copy16(HB + so0 + (kb), (pB) + dd0);         \
    async_copy16(HA + so1 + (kb), (pA) + dd1);         \
    async_copy16(HB + so1 + (kb), (pB) + dd1);         \
    async_copy16(HA + so2 + (kb), (pA) + dd2);         \
    async_copy16(HB + so2 + (kb), (pB) + dd2);         \
    async_copy16(HA + so3 + (kb), (pA) + dd3);         \
    async_copy16(HB + so3 + (kb), (pB) + dd3);         \
}

#define CKK(cA, cB, kk) {                                        \
    short8 b0 = *(const short8*)&(cB)[offB[kk][0]];              \
    short8 b1 = *(const short8*)&(cB)[offB[kk][1]];              \
    short8 b2 = *(const short8*)&(cB)[offB[kk][2]];              \
    short8 b3 = *(const short8*)&(cB)[offB[kk][3]];              \
    {                                                            \
        short8 a0 = *(const short8*)&(cA)[offA[kk][0]];          \
        short8 a1 = *(const short8*)&(cA)[offA[kk][1]];          \
        short8 a2 = *(const short8*)&(cA)[offA[kk][2]];          \
        short8 a3 = *(const short8*)&(cA)[offA[kk][3]];          \
        MF_ROW(0, a0) MF_ROW(1, a1) MF_ROW(2, a2) MF_ROW(3, a3)  \
    }                                                            \
    {                                                            \
        short8 a0 = *(const short8*)&(cA)[offA[kk][4]];          \
        short8 a1 = *(const short8*)&(cA)[offA[kk][5]];          \
        short8 a2 = *(const short8*)&(cA)[offA[kk][6]];          \
        short8 a3 = *(const short8*)&(cA)[offA[kk][7]];          \
        MF_ROW(4, a0) MF_ROW(5, a1) MF_ROW(6, a2) MF_ROW(7, a3)  \
    }                                                            \
}

#define COMPUTE(cA, cB) { CKK(cA, cB, 0) CKK(cA, cB, 1) }

#define BARRIER() { __builtin_amdgcn_s_barrier(); asm volatile("" ::: "memory"); }

__global__ __launch_bounds__(512, 2) void gram_kernel(const u16* __restrict__ H,
                                                      float* __restrict__ Mpart,
                                                      float* __restrict__ Spart,
                                                      const float* __restrict__ Pos,
                                                      float* __restrict__ out,
                                                      unsigned* __restrict__ ticket) {
    __shared__ u16 As[2 * BUF];    // 64 KB
    __shared__ u16 Bs[2 * BUF];    // 64 KB
    __shared__ unsigned shTicket;

    const int tid  = threadIdx.x;
    const int lane = tid & 63;
    const int wid  = tid >> 6;        // 0..7
    const int quad = lane >> 4;
    const int ln15 = lane & 15;
    const int wr = wid >> 2;          // 0..1 : 128-row strip
    const int wc = wid & 3;           // 0..3 : 64-col strip

    // bijective XCD swizzle over 512 blocks (512 % 8 == 0)
    const int bswz = (blockIdx.x & 7) * (GRIDG / 8) + (blockIdx.x >> 3);

    // staging per-thread offsets (4 chunks/thread per matrix per K-tile):
    // chunk c = j*512+tid; row=c>>3, pos=c&7; src k-slot = pos^(row&7);
    // dest = c*16B (linear -> wave-uniform base + lane*16B as required).
    const int c0 = tid, c1 = tid + 512, c2 = tid + 1024, c3 = tid + 1536;
    const size_t so0 = (size_t)(c0 >> 3) * DD + ((c0 & 7) ^ ((c0 >> 3) & 7)) * 8;
    const size_t so1 = (size_t)(c1 >> 3) * DD + ((c1 & 7) ^ ((c1 >> 3) & 7)) * 8;
    const size_t so2 = (size_t)(c2 >> 3) * DD + ((c2 & 7) ^ ((c2 >> 3) & 7)) * 8;
    const size_t so3 = (size_t)(c3 >> 3) * DD + ((c3 & 7) ^ ((c3 >> 3) & 7)) * 8;
    const int dd0 = c0 * 8, dd1 = c1 * 8, dd2 = c2 * 8, dd3 = c3 * 8;

    // fragment read offsets (elements), conflict-free (r2-verified)
    int offA[2][8], offB[2][4];
#pragma unroll
    for (int kk = 0; kk < 2; kk++) {
#pragma unroll
        for (int m = 0; m < 8; m++) {
            int r = wr * 128 + m * 16 + ln15;
            offA[kk][m] = (r * 8 + ((kk * 4 + quad) ^ (r & 7))) * 8;
        }
#pragma unroll
        for (int n = 0; n < 4; n++) {
            int r = wc * 64 + n * 16 + ln15;
            offB[kk][n] = (r * 8 + ((kk * 4 + quad) ^ (r & 7))) * 8;
        }
    }

    for (int tile = bswz; tile < NTILE; tile += GRIDG) {
        __syncthreads();   // protect LDS reuse across the 2-tile loop

        // lower-triangle decode
        int t = tile;
        int bi = (int)((sqrtf(8.0f * (float)t + 1.0f) - 1.0f) * 0.5f);
        while ((bi + 1) * (bi + 2) / 2 <= t) bi++;
        while (bi * (bi + 1) / 2 > t) bi--;
        const int bj = t - bi * (bi + 1) / 2;
        const bool diag = (bi == bj);
        const int biBase = bi * 256, bjBase = bj * 256;

        const u16* __restrict__ HA = H + (size_t)biBase * DD;
        const u16* __restrict__ HB = H + (size_t)bjBase * DD;

        floatx4 acc[8][4];
#pragma unroll
        for (int i = 0; i < 8; i++)
#pragma unroll
            for (int j = 0; j < 4; j++) acc[i][j] = (floatx4)0.0f;

        // prologue: tiles 0 and 1 in flight (16 loads/thread)
        STAGE_T(0,  &As[0],   &Bs[0]);
        STAGE_T(64, &As[BUF], &Bs[BUF]);

        // main loop: K-tiles 0..6; tile 7 peeled with full drain.
        for (int kt = 0; kt < 7; ++kt) {
            const u16* cA = &As[(kt & 1) * BUF];
            const u16* cB = &Bs[(kt & 1) * BUF];
            u16* sA = &As[(kt & 1) * BUF];
            u16* sB = &Bs[(kt & 1) * BUF];
            VMWAIT(8);              // oldest 8 = tile kt fully landed
            BARRIER();
            COMPUTE(cA, cB);        // 24 ds_read_b128 + 64 MFMA, compiler-scheduled
            BARRIER();              // all waves done reading buf (kt&1)
            if (kt < 6) { int kb = (kt + 2) * 64; STAGE_T(kb, sA, sB); }
        }
        VMWAIT(0);
        BARRIER();
        COMPUTE((&As[BUF]), (&Bs[BUF]));
        __syncthreads();

        // scale in place; mask self-similarity on diagonal tiles
        // C/D layout: row = wr*128 + m*16 + quad*4 + g, col = wc*64 + n*16 + ln15
#pragma unroll
        for (int m = 0; m < 8; m++)
#pragma unroll
            for (int n = 0; n < 4; n++)
#pragma unroll
                for (int g = 0; g < 4; g++) {
                    float v = SCALE * acc[m][n][g];
                    if (diag) {
                        int lrow = wr * 128 + m * 16 + quad * 4 + g;
                        int lcol = wc * 64 + n * 16 + ln15;
                        if (lrow == lcol) v = -FLT_MAX;
                    }
                    acc[m][n][g] = v;
                }

        // epilogue scratch aliases onto As (staging fully drained above)
        float* Rm = (float*)&As[0];      // [4][256]
        float* Rs = Rm + 1024;           // [4][256]
        float* Cm = Rs + 1024;           // [2][256]
        float* Cs = Cm + 512;            // [2][256]

        // row pass: per-row max+sumexp over this wave's 64 cols
#pragma unroll
        for (int m = 0; m < 8; m++) {
#pragma unroll
            for (int g = 0; g < 4; g++) {
                float vmax = fmaxf(fmaxf(acc[m][0][g], acc[m][1][g]),
                                   fmaxf(acc[m][2][g], acc[m][3][g]));
#pragma unroll
                for (int msk = 1; msk < 16; msk <<= 1)
                    vmax = fmaxf(vmax, __shfl_xor(vmax, msk));
                float s = __expf(acc[m][0][g] - vmax) + __expf(acc[m][1][g] - vmax)
                        + __expf(acc[m][2][g] - vmax) + __expf(acc[m][3][g] - vmax);
#pragma unroll
                for (int msk = 1; msk < 16; msk <<= 1) s += __shfl_xor(s, msk);
                if (ln15 == 0) {
                    int x = wr * 128 + m * 16 + quad * 4 + g;
                    Rm[wc * 256 + x] = vmax; Rs[wc * 256 + x] = s;
                }
            }
        }

        // col pass (transpose tile): per-col max+sumexp over this wave's 128 rows
        if (!diag) {
#pragma unroll
            for (int n = 0; n < 4; n++) {
                float cm = -FLT_MAX;
#pragma unroll
                for (int m = 0; m < 8; m++)
#pragma unroll
                    for (int g = 0; g < 4; g++) cm = fmaxf(cm, acc[m][n][g]);
                cm = fmaxf(cm, __shfl_xor(cm, 16));
                cm = fmaxf(cm, __shfl_xor(cm, 32));
                float s = 0.0f;
#pragma unroll
                for (int m = 0; m < 8; m++)
#pragma unroll
                    for (int g = 0; g < 4; g++) s += __expf(acc[m][n][g] - cm);
                s += __shfl_xor(s, 16);
                s += __shfl_xor(s, 32);
                if (quad == 0) {
                    int y = wc * 64 + n * 16 + ln15;
                    Cm[wr * 256 + y] = cm; Cs[wr * 256 + y] = s;
                }
            }
        }
        __syncthreads();

        // merge wave strips, write slot-major partials: Mpart[slot*NN + row]
        if (tid < 256) {
            float m0 = Rm[tid], m1 = Rm[256 + tid], m2 = Rm[512 + tid], m3 = Rm[768 + tid];
            float mm = fmaxf(fmaxf(m0, m1), fmaxf(m2, m3));
            float s = Rs[tid] * __expf(m0 - mm) + Rs[256 + tid] * __expf(m1 - mm)
                    + Rs[512 + tid] * __expf(m2 - mm) + Rs[768 + tid] * __expf(m3 - mm);
            Mpart[(size_t)bj * NN + biBase + tid] = mm;
            Spart[(size_t)bj * NN + biBase + tid] = s;
        } else if (!diag) {
            int y = tid - 256;
            float m0 = Cm[y], m1 = Cm[256 + y];
            float mm = fmaxf(m0, m1);
            float s = Cs[y] * __expf(m0 - mm) + Cs[256 + y] * __expf(m1 - mm);
            Mpart[(size_t)bi * NN + bjBase + y] = mm;
            Spart[(size_t)bi * NN + bjBase + y] = s;
        }
    }

    // ---- publish + ticket; last NDUTY finishers run the fused LSE ----
    __threadfence();                       // release partials (device scope)
    __syncthreads();
    if (tid == 0) shTicket = atomicAdd(ticket, 1u);
    __syncthreads();
    if (shTicket >= (unsigned)(GRIDG - NDUTY)) {
        if (tid == 0) {
            while (atomicAdd(ticket, 0u) < (unsigned)GRIDG)
                __builtin_amdgcn_s_sleep(2);
        }
        __syncthreads();
        __threadfence();                   // acquire
        const int idx = (int)shTicket - (GRIDG - NDUTY);   // 0..31
        float v = 0.0f;
        if (tid < 256) {
            int r = idx * 256 + tid;
            float m = -FLT_MAX, s = 0.0f;
#pragma unroll 8
            for (int c = 0; c < 32; c++) {
                float mc = Mpart[(size_t)c * NN + r];  // lane-contiguous, coalesced
                float sc = Spart[(size_t)c * NN + r];
                float mn = fmaxf(m, mc);
                s = s * __expf(m - mn) + sc * __expf(mc - mn);
                m = mn;
            }
            v = m + logf(s);
            if (tid < 64) v += -4.0f * Pos[idx * 64 + tid];
        }
        float* red = (float*)&As[0];
        red[tid] = v;
        __syncthreads();
        for (int st = 256; st > 0; st >>= 1) {
            if (tid < st) red[tid] += red[tid + st];
            __syncthreads();
        }
        if (tid == 0) atomicAdd(out, red[0] * (1.0f / (float)NN));
    }
}

extern "C" void kernel_launch(void* const* d_in, const int* in_sizes, int n_in,
                              void* d_out, int out_size, void* d_ws, size_t ws_size,
                              hipStream_t stream) {
    const float* hi = (const float*)d_in[0];
    const float* hj = (const float*)d_in[1];
    float* out = (float*)d_out;

    u16*      H      = (u16*)d_ws;                                          // 8 MB
    float*    Mpart  = (float*)((char*)d_ws + (size_t)8 * 1024 * 1024);     // 1 MB used
    float*    Spart  = (float*)((char*)d_ws + (size_t)10 * 1024 * 1024);    // 1 MB used
    float*    Pos    = (float*)((char*)d_ws + (size_t)12 * 1024 * 1024);    // 8 KB
    unsigned* ticket = (unsigned*)((char*)d_ws + (size_t)13 * 1024 * 1024); // 4 B

    convert_pos_kernel<<<2048, 256, 0, stream>>>(hi, hj, H, Pos, out, ticket);

    gram_kernel<<<GRIDG, 512, 0, stream>>>(H, Mpart, Spart, Pos, out, ticket);
}